// Round 11
// baseline (643.434 us; speedup 1.0000x reference)
//
#include <hip/hip_runtime.h>
#include <hip/hip_bf16.h>

// ShiftWindowMSA fused pipeline for MI355X (gfx950).
// R11: 12-wave blocks (768 thr, 3 waves/SIMD), wave = one head (32 cols).
// Each wave runs TWO independent K-chains concurrently (var0: k||v sharing A
// frags; var1/proj: split-K), wave-private B dbufs via global_load_lds,
// counted vmcnt(4), no K-loop barriers. Epilogues bounce through the dead
// B-dbuf in LDS -> full-cacheline 16B stores. attn gets the same store bounce.

typedef __attribute__((ext_vector_type(8))) short short8;
typedef __attribute__((ext_vector_type(4))) float floatx4;

#define MFMA16(a, b, c) __builtin_amdgcn_mfma_f32_16x16x32_bf16(a, b, c, 0, 0, 0)

__device__ __forceinline__ short f2bf(float f) {
    __hip_bfloat16 h = __float2bfloat16(f);
    return *reinterpret_cast<short*>(&h);
}

// packed fp32->bf16 RNE
__device__ __forceinline__ unsigned cvt2bf(float lo, float hi) {
    unsigned r;
    asm("v_cvt_pk_bf16_f32 %0, %1, %2" : "=v"(r) : "v"(lo), "v"(hi));
    return r;
}

__device__ __forceinline__ void glds16(const void* g, void* l) {
    __builtin_amdgcn_global_load_lds(
        (const __attribute__((address_space(1))) void*)g,
        (__attribute__((address_space(3))) void*)l, 16, 0, 0);
}

// ---------------- prep kernels ----------------

__global__ __launch_bounds__(256) void prep_wt(const float* __restrict__ Wqkv,
                                               const float* __restrict__ Wskip,
                                               short* __restrict__ Wt) {
    int tid = blockIdx.x * 256 + threadIdx.x;  // 384*144 = 55296
    if (tid >= 384 * 144) return;
    int k = tid / 144;
    int n8 = (tid % 144) * 8;
#pragma unroll
    for (int e = 0; e < 8; e++) {
        int n = n8 + e;
        float v = (n < 768) ? Wqkv[k * 768 + n]
                            : Wskip[k * 384 + (n - 768)] * 0.17677669529663687f;
        Wt[(size_t)n * 384 + k] = f2bf(v);
    }
}

__global__ __launch_bounds__(256) void prep_wtp(const float* __restrict__ Wproj,
                                                short* __restrict__ WtP) {
    int tid = blockIdx.x * 256 + threadIdx.x;  // 384*48 = 18432
    if (tid >= 384 * 48) return;
    int k = tid / 48;
    int n8 = (tid % 48) * 8;
#pragma unroll
    for (int e = 0; e < 8; e++) {
        int n = n8 + e;
        WtP[(size_t)n * 384 + k] = f2bf(Wproj[k * 384 + n]);
    }
}

__global__ __launch_bounds__(256) void prep_bias(const float* __restrict__ rpb,
                                                 float* __restrict__ bias64) {
    int tid = blockIdx.x * 256 + threadIdx.x;  // 12*64*64 = 49152
    if (tid >= 49152) return;
    int h = tid >> 12;
    int rem = tid & 4095;
    int i = rem >> 6, kk = rem & 63;
    int j = 63 - kk;
    int ridx = 15 * (i >> 3) + (i & 7) + 15 * (j >> 3) + (j & 7);
    bias64[tid] = rpb[ridx * 12 + h];
}

// ---------------- gemm_qkv ----------------
// LDS: A[64][384] bf16 @0 (24576 sh); 12 waves x (2 chains x 2x1024 sh) @24576.
// Total 73728 sh = 144 KB -> 1 block/CU, 12 waves (3/SIMD).
__global__ __launch_bounds__(768) void gemm_qkv(
    const float* __restrict__ xq, const float* __restrict__ xs,
    const short* __restrict__ Wt,
    const float* __restrict__ bqkv, const float* __restrict__ bskip,
    short* __restrict__ kbuf, short* __restrict__ vtbuf, short* __restrict__ qbuf) {
    __shared__ short smem[73728];

    const int win = blockIdx.x;
    const int var = blockIdx.y;          // 0: A=query -> k,v; 1: A=skip -> q
    const float* __restrict__ src = var ? xs : xq;

    const int tid = threadIdx.x, lane = tid & 63, wid = tid >> 6;  // wid = head
    const int l15 = lane & 15, g4 = lane >> 4;
    const int al7 = l15 & 7;
    const int brd = (g4 ^ ((l15 ^ (l15 >> 2)) & 3)) * 8;

    // ---- A gather: 64 rows x 384 fp32 (shift-window permuted) -> bf16 LDS ----
    {
        int r = tid / 12, slot = tid - r * 12;
        int b = win / 144, wr = win % 144;
        int wy = wr / 12, wx = wr % 12;
        int yy = wy * 8 + (r >> 3) + 4; if (yy >= 96) yy -= 96;
        int xx = wx * 8 + (r & 7) + 4;  if (xx >= 96) xx -= 96;
        const float* rbase = src + ((size_t)b * 9216 + yy * 96 + xx) * 384;
        short* lrow = smem + r * 384;
        int r7 = r & 7;
#pragma unroll
        for (int j = 0; j < 4; j++) {
            int c = slot * 4 + j;
            float4 f0 = *(const float4*)(rbase + c * 8);
            float4 f1 = *(const float4*)(rbase + c * 8 + 4);
            uint4 u;
            u.x = cvt2bf(f0.x, f0.y); u.y = cvt2bf(f0.z, f0.w);
            u.z = cvt2bf(f1.x, f1.y); u.w = cvt2bf(f1.z, f1.w);
            *(uint4*)(lrow + ((c ^ r7) * 8)) = u;
        }
    }

    // ---- B staging roles: 2 glds of 1 KB per 32-row x 32-k slice ----
    int bso[2];
#pragma unroll
    for (int j = 0; j < 2; j++) {
        int c = j * 64 + lane;
        int brow = c >> 2, bs = c & 3;
        int sw = (brow ^ (brow >> 2)) & 3;
        bso[j] = brow * 384 + (bs ^ sw) * 8;
    }
    short* ds0 = smem + 24576 + wid * 4096;   // chain0 dbuf: 2 x 1024 sh
    short* ds1 = ds0 + 2048;                  // chain1 dbuf

    const int h = wid;

    if (var == 0) {
        const short* sK = Wt + (size_t)(h * 32) * 384;
        const short* sV = Wt + (size_t)(384 + h * 32) * 384;
        // prologue: stage steps 0,1 of both chains
#pragma unroll
        for (int j = 0; j < 2; j++) {
            glds16(sK + bso[j], ds0 + j * 512);
            glds16(sV + bso[j], ds1 + j * 512);
            glds16(sK + bso[j] + 32, ds0 + 1024 + j * 512);
            glds16(sV + bso[j] + 32, ds1 + 1024 + j * 512);
        }
        __syncthreads();

        floatx4 aK[2][4], aV[2][4];
#pragma unroll
        for (int a = 0; a < 2; a++)
#pragma unroll
            for (int b = 0; b < 4; b++)
#pragma unroll
                for (int r = 0; r < 4; r++) { aK[a][b][r] = 0.f; aV[a][b][r] = 0.f; }

#pragma unroll
        for (int kt = 0; kt < 12; ++kt) {
            if (kt < 11) asm volatile("s_waitcnt vmcnt(4)" ::: "memory");
            else         asm volatile("s_waitcnt vmcnt(0)" ::: "memory");
            const int choff = ((kt * 4 + g4) ^ al7) * 8;
            short8 af[4], bK[2], bV[2];
#pragma unroll
            for (int b = 0; b < 4; b++)
                af[b] = *(const short8*)(smem + (b * 16 + l15) * 384 + choff);
            int hb = (kt & 1) * 1024;
#pragma unroll
            for (int a = 0; a < 2; a++) {
                bK[a] = *(const short8*)(ds0 + hb + (a * 16 + l15) * 32 + brd);
                bV[a] = *(const short8*)(ds1 + hb + (a * 16 + l15) * 32 + brd);
            }
            __builtin_amdgcn_sched_barrier(0);
            asm volatile("s_waitcnt lgkmcnt(0)" ::: "memory");
            if (kt < 10) {
                int ko = (kt + 2) * 32;
#pragma unroll
                for (int j = 0; j < 2; j++) {
                    glds16(sK + bso[j] + ko, ds0 + hb + j * 512);
                    glds16(sV + bso[j] + ko, ds1 + hb + j * 512);
                }
            }
            __builtin_amdgcn_sched_barrier(0);
#pragma unroll
            for (int a = 0; a < 2; a++)
#pragma unroll
                for (int b = 0; b < 4; b++) {
                    aK[a][b] = MFMA16(bK[a], af[b], aK[a][b]);
                    aV[a][b] = MFMA16(af[b], bV[a], aV[a][b]);
                }
        }

        // ---- k epilogue: bounce [64t][32d] through ds0, full-line stores ----
#pragma unroll
        for (int a = 0; a < 2; a++) {
            float4 bv = *(const float4*)(bqkv + h * 32 + a * 16 + g4 * 4);
#pragma unroll
            for (int b = 0; b < 4; b++) {
                uint2 pk;
                pk.x = cvt2bf(aK[a][b][0] + bv.x, aK[a][b][1] + bv.y);
                pk.y = cvt2bf(aK[a][b][2] + bv.z, aK[a][b][3] + bv.w);
                *(uint2*)(ds0 + (b * 16 + l15) * 32 + a * 16 + g4 * 4) = pk;
            }
        }
        // ---- v epilogue: bounce [32d][64t] through ds1 ----
#pragma unroll
        for (int a = 0; a < 2; a++) {
#pragma unroll
            for (int b = 0; b < 4; b++) {
                float bvs = bqkv[384 + h * 32 + a * 16 + l15];
                uint2 pk;
                pk.x = cvt2bf(aV[a][b][0] + bvs, aV[a][b][1] + bvs);
                pk.y = cvt2bf(aV[a][b][2] + bvs, aV[a][b][3] + bvs);
                *(uint2*)(ds1 + (a * 16 + l15) * 64 + b * 16 + g4 * 4) = pk;
            }
        }
        asm volatile("s_waitcnt lgkmcnt(0)" ::: "memory");
        short* dk = kbuf + (size_t)(win * 12 + h) * 2048 + lane * 32;
        const short* rk = ds0 + lane * 32;
        int vo = (lane >> 1) * 64 + (lane & 1) * 32;
        short* dv = vtbuf + (size_t)(win * 12 + h) * 2048 + vo;
        const short* rv = ds1 + vo;
#pragma unroll
        for (int j = 0; j < 4; j++) {
            *(short8*)(dk + j * 8) = *(const short8*)(rk + j * 8);
            *(short8*)(dv + j * 8) = *(const short8*)(rv + j * 8);
        }
    } else {
        // ---- q: split-K dual chain (K 0..192 | 192..384) ----
        const short* sQ = Wt + (size_t)(768 + h * 32) * 384;
#pragma unroll
        for (int j = 0; j < 2; j++) {
            glds16(sQ + bso[j], ds0 + j * 512);
            glds16(sQ + bso[j] + 192, ds1 + j * 512);
            glds16(sQ + bso[j] + 32, ds0 + 1024 + j * 512);
            glds16(sQ + bso[j] + 192 + 32, ds1 + 1024 + j * 512);
        }
        __syncthreads();

        floatx4 qA[2][4], qB[2][4];
#pragma unroll
        for (int a = 0; a < 2; a++)
#pragma unroll
            for (int b = 0; b < 4; b++)
#pragma unroll
                for (int r = 0; r < 4; r++) { qA[a][b][r] = 0.f; qB[a][b][r] = 0.f; }

#pragma unroll
        for (int kt = 0; kt < 6; ++kt) {
            if (kt < 5) asm volatile("s_waitcnt vmcnt(4)" ::: "memory");
            else        asm volatile("s_waitcnt vmcnt(0)" ::: "memory");
            const int cA = ((kt * 4 + g4) ^ al7) * 8;
            const int cB = ((24 + kt * 4 + g4) ^ al7) * 8;
            short8 afA[4], afB[4], bA[2], bB[2];
#pragma unroll
            for (int b = 0; b < 4; b++) {
                afA[b] = *(const short8*)(smem + (b * 16 + l15) * 384 + cA);
                afB[b] = *(const short8*)(smem + (b * 16 + l15) * 384 + cB);
            }
            int hb = (kt & 1) * 1024;
#pragma unroll
            for (int a = 0; a < 2; a++) {
                bA[a] = *(const short8*)(ds0 + hb + (a * 16 + l15) * 32 + brd);
                bB[a] = *(const short8*)(ds1 + hb + (a * 16 + l15) * 32 + brd);
            }
            __builtin_amdgcn_sched_barrier(0);
            asm volatile("s_waitcnt lgkmcnt(0)" ::: "memory");
            if (kt < 4) {
                int ko = (kt + 2) * 32;
#pragma unroll
                for (int j = 0; j < 2; j++) {
                    glds16(sQ + bso[j] + ko, ds0 + hb + j * 512);
                    glds16(sQ + bso[j] + 192 + ko, ds1 + hb + j * 512);
                }
            }
            __builtin_amdgcn_sched_barrier(0);
#pragma unroll
            for (int a = 0; a < 2; a++)
#pragma unroll
                for (int b = 0; b < 4; b++) {
                    qA[a][b] = MFMA16(bA[a], afA[b], qA[a][b]);
                    qB[a][b] = MFMA16(bB[a], afB[b], qB[a][b]);
                }
        }

        const float scl = 0.17677669529663687f;
#pragma unroll
        for (int a = 0; a < 2; a++) {
            float4 bv = *(const float4*)(bskip + h * 32 + a * 16 + g4 * 4);
#pragma unroll
            for (int b = 0; b < 4; b++) {
                floatx4 s = qA[a][b] + qB[a][b];
                uint2 pk;
                pk.x = cvt2bf(s[0] + bv.x * scl, s[1] + bv.y * scl);
                pk.y = cvt2bf(s[2] + bv.z * scl, s[3] + bv.w * scl);
                *(uint2*)(ds0 + (b * 16 + l15) * 32 + a * 16 + g4 * 4) = pk;
            }
        }
        asm volatile("s_waitcnt lgkmcnt(0)" ::: "memory");
        short* dq = qbuf + (size_t)(win * 12 + h) * 2048 + lane * 32;
        const short* rq = ds0 + lane * 32;
#pragma unroll
        for (int j = 0; j < 4; j++)
            *(short8*)(dq + j * 8) = *(const short8*)(rq + j * 8);
    }
}

// ---------------- attention ----------------
__global__ __launch_bounds__(256) void attn_kernel(
    const short* __restrict__ kbuf, const short* __restrict__ vtbuf,
    const short* __restrict__ qbuf, const float* __restrict__ bias64,
    short* __restrict__ aout, int ntask) {
    __shared__ short lps[18432];  // 4 waves x 64 x 72
    int lane = threadIdx.x & 63, wid = threadIdx.x >> 6;
    int task = blockIdx.x * 4 + wid;
    if (task >= ntask) return;
    int win = task / 12, head = task % 12;
    int l15 = lane & 15, g4 = lane >> 4;

    const short* kb = kbuf + (size_t)task * 2048;
    const short* qb = qbuf + (size_t)task * 2048;
    const short* vb = vtbuf + (size_t)task * 2048;

    short8 kf[4], qf[4], vf[2][2];
#pragma unroll
    for (int mi = 0; mi < 4; mi++)
        kf[mi] = *(const short8*)(kb + (mi * 16 + l15) * 32 + g4 * 8);
#pragma unroll
    for (int nj = 0; nj < 4; nj++)
        qf[nj] = *(const short8*)(qb + (nj * 16 + l15) * 32 + g4 * 8);
#pragma unroll
    for (int ma = 0; ma < 2; ma++)
#pragma unroll
        for (int ks = 0; ks < 2; ks++)
            vf[ma][ks] = *(const short8*)(vb + (ma * 16 + l15) * 64 + ks * 32 + g4 * 8);

    floatx4 st[4][4];
#pragma unroll
    for (int mi = 0; mi < 4; mi++)
#pragma unroll
        for (int nj = 0; nj < 4; nj++)
#pragma unroll
            for (int r = 0; r < 4; r++) st[mi][nj][r] = 0.f;

#pragma unroll
    for (int mi = 0; mi < 4; mi++)
#pragma unroll
        for (int nj = 0; nj < 4; nj++)
            st[mi][nj] = MFMA16(kf[mi], qf[nj], st[mi][nj]);  // S^T[kk][i]

    const float* bb = bias64 + head * 4096;
#pragma unroll
    for (int nj = 0; nj < 4; nj++) {
        int i = nj * 16 + l15;
#pragma unroll
        for (int mi = 0; mi < 4; mi++) {
            floatx4 b4 = *(const floatx4*)(bb + i * 64 + mi * 16 + g4 * 4);
            st[mi][nj] += b4;
        }
    }

    int wr = win % 144;
    int wy = wr / 12, wx = wr % 12;
    if (wy == 11 || wx == 11) {
        int wy11 = (wy == 11), wx11 = (wx == 11);
        int ri[4];
#pragma unroll
        for (int nj = 0; nj < 4; nj++) {
            int t = nj * 16 + l15;
            int hh = wy11 ? (((t >> 3) >= 4) ? 2 : 1) : 0;
            int ww = wx11 ? (((t & 7) >= 4) ? 2 : 1) : 0;
            ri[nj] = hh * 3 + ww;
        }
#pragma unroll
        for (int mi = 0; mi < 4; mi++)
#pragma unroll
            for (int r = 0; r < 4; r++) {
                int t = mi * 16 + g4 * 4 + r;
                int hh = wy11 ? (((t >> 3) >= 4) ? 2 : 1) : 0;
                int ww = wx11 ? (((t & 7) >= 4) ? 2 : 1) : 0;
                int rk = hh * 3 + ww;
#pragma unroll
                for (int nj = 0; nj < 4; nj++)
                    if (rk != ri[nj]) st[mi][nj][r] -= 100.0f;
            }
    }

    float rden[4];
#pragma unroll
    for (int nj = 0; nj < 4; nj++) {
        float m = -1e30f;
#pragma unroll
        for (int mi = 0; mi < 4; mi++)
#pragma unroll
            for (int r = 0; r < 4; r++) m = fmaxf(m, st[mi][nj][r]);
        m = fmaxf(m, __shfl_xor(m, 16));
        m = fmaxf(m, __shfl_xor(m, 32));
        float s = 0.f;
#pragma unroll
        for (int mi = 0; mi < 4; mi++)
#pragma unroll
            for (int r = 0; r < 4; r++) {
                float p = __expf(st[mi][nj][r] - m);
                st[mi][nj][r] = p;
                s += p;
            }
        s += __shfl_xor(s, 16);
        s += __shfl_xor(s, 32);
        rden[nj] = 1.0f / s;
    }

    short* Lp = lps + wid * 4608;  // [64][72]
#pragma unroll
    for (int mi = 0; mi < 4; mi++)
#pragma unroll
        for (int nj = 0; nj < 4; nj++) {
            uint2 pk;
            pk.x = cvt2bf(st[mi][nj][0], st[mi][nj][1]);
            pk.y = cvt2bf(st[mi][nj][2], st[mi][nj][3]);
            *(uint2*)(Lp + (nj * 16 + l15) * 72 + mi * 16 + g4 * 4) = pk;
        }

    floatx4 o[2][4];
#pragma unroll
    for (int ma = 0; ma < 2; ma++)
#pragma unroll
        for (int nj = 0; nj < 4; nj++)
#pragma unroll
            for (int r = 0; r < 4; r++) o[ma][nj][r] = 0.f;
#pragma unroll
    for (int ks = 0; ks < 2; ks++) {
        short8 pb[4];
#pragma unroll
        for (int nj = 0; nj < 4; nj++)
            pb[nj] = *(const short8*)(Lp + (nj * 16 + l15) * 72 + ks * 32 + g4 * 8);
#pragma unroll
        for (int ma = 0; ma < 2; ma++)
#pragma unroll
            for (int nj = 0; nj < 4; nj++)
                o[ma][nj] = MFMA16(vf[ma][ks], pb[nj], o[ma][nj]);
    }

    // o bounce: Lp[i][d] (stride 72) -> full-line 16B stores
#pragma unroll
    for (int ma = 0; ma < 2; ma++)
#pragma unroll
        for (int nj = 0; nj < 4; nj++) {
            uint2 pk;
            pk.x = cvt2bf(o[ma][nj][0] * rden[nj], o[ma][nj][1] * rden[nj]);
            pk.y = cvt2bf(o[ma][nj][2] * rden[nj], o[ma][nj][3] * rden[nj]);
            *(uint2*)(Lp + (nj * 16 + l15) * 72 + ma * 16 + g4 * 4) = pk;
        }
    asm volatile("s_waitcnt lgkmcnt(0)" ::: "memory");
    short* ob = aout + (size_t)win * 24576 + lane * 384 + head * 32;
    const short* ro = Lp + lane * 72;
#pragma unroll
    for (int j = 0; j < 4; j++)
        *(short8*)(ob + j * 8) = *(const short8*)(ro + j * 8);
}

// ---------------- gemm_proj ----------------
// Same 12-wave split-K structure; A (bf16) via glds; fp32 scatter epilogue.
__global__ __launch_bounds__(768) void gemm_proj(
    const short* __restrict__ aout, const short* __restrict__ WtP,
    const float* __restrict__ bproj, float* __restrict__ out) {
    __shared__ short smem[73728];

    const int win = blockIdx.x;
    const int m0 = win * 64;
    const int tid = threadIdx.x, lane = tid & 63, wid = tid >> 6;
    const int l15 = lane & 15, g4 = lane >> 4;
    const int al7 = l15 & 7;
    const int brd = (g4 ^ ((l15 ^ (l15 >> 2)) & 3)) * 8;

    // ---- A via glds: 48 issues of 1 KB (4 per wave), pre-swizzled source ----
#pragma unroll
    for (int j = 0; j < 4; j++) {
        int i = wid * 4 + j;
        int c = i * 64 + lane;
        int row = c / 48, ch = c - row * 48;
        const short* s = aout + (size_t)(m0 + row) * 384 + ((ch ^ (row & 7)) * 8);
        glds16(s, smem + i * 512);
    }

    int bso[2];
#pragma unroll
    for (int j = 0; j < 2; j++) {
        int c = j * 64 + lane;
        int brow = c >> 2, bs = c & 3;
        int sw = (brow ^ (brow >> 2)) & 3;
        bso[j] = brow * 384 + (bs ^ sw) * 8;
    }
    short* ds0 = smem + 24576 + wid * 4096;
    short* ds1 = ds0 + 2048;
    const short* sB = WtP + (size_t)(wid * 32) * 384;

#pragma unroll
    for (int j = 0; j < 2; j++) {
        glds16(sB + bso[j], ds0 + j * 512);
        glds16(sB + bso[j] + 192, ds1 + j * 512);
        glds16(sB + bso[j] + 32, ds0 + 1024 + j * 512);
        glds16(sB + bso[j] + 192 + 32, ds1 + 1024 + j * 512);
    }
    __syncthreads();

    floatx4 qA[2][4], qB[2][4];
#pragma unroll
    for (int a = 0; a < 2; a++)
#pragma unroll
        for (int b = 0; b < 4; b++)
#pragma unroll
            for (int r = 0; r < 4; r++) { qA[a][b][r] = 0.f; qB[a][b][r] = 0.f; }

#pragma unroll
    for (int kt = 0; kt < 6; ++kt) {
        if (kt < 5) asm volatile("s_waitcnt vmcnt(4)" ::: "memory");
        else        asm volatile("s_waitcnt vmcnt(0)" ::: "memory");
        const int cA = ((kt * 4 + g4) ^ al7) * 8;
        const int cB = ((24 + kt * 4 + g4) ^ al7) * 8;
        short8 afA[4], afB[4], bA[2], bB[2];
#pragma unroll
        for (int b = 0; b < 4; b++) {
            afA[b] = *(const short8*)(smem + (b * 16 + l15) * 384 + cA);
            afB[b] = *(const short8*)(smem + (b * 16 + l15) * 384 + cB);
        }
        int hb = (kt & 1) * 1024;
#pragma unroll
        for (int a = 0; a < 2; a++) {
            bA[a] = *(const short8*)(ds0 + hb + (a * 16 + l15) * 32 + brd);
            bB[a] = *(const short8*)(ds1 + hb + (a * 16 + l15) * 32 + brd);
        }
        __builtin_amdgcn_sched_barrier(0);
        asm volatile("s_waitcnt lgkmcnt(0)" ::: "memory");
        if (kt < 4) {
            int ko = (kt + 2) * 32;
#pragma unroll
            for (int j = 0; j < 2; j++) {
                glds16(sB + bso[j] + ko, ds0 + hb + j * 512);
                glds16(sB + bso[j] + 192 + ko, ds1 + hb + j * 512);
            }
        }
        __builtin_amdgcn_sched_barrier(0);
#pragma unroll
        for (int a = 0; a < 2; a++)
#pragma unroll
            for (int b = 0; b < 4; b++) {
                qA[a][b] = MFMA16(bA[a], afA[b], qA[a][b]);
                qB[a][b] = MFMA16(bB[a], afB[b], qB[a][b]);
            }
    }

    const int b_img = win / 144, wrw = win % 144;
    const int wy = wrw / 12, wx = wrw % 12;
#pragma unroll
    for (int a = 0; a < 2; a++) {
        int n = wid * 32 + a * 16 + g4 * 4;
        float4 bv = *(const float4*)(bproj + n);
#pragma unroll
        for (int b = 0; b < 4; b++) {
            int t = b * 16 + l15;
            int yy = wy * 8 + (t >> 3) + 4; if (yy >= 96) yy -= 96;
            int xx = wx * 8 + (t & 7) + 4;  if (xx >= 96) xx -= 96;
            floatx4 o = qA[a][b] + qB[a][b];
            o[0] += bv.x; o[1] += bv.y; o[2] += bv.z; o[3] += bv.w;
            *(floatx4*)(&out[((size_t)b_img * 9216 + yy * 96 + xx) * 384 + n]) = o;
        }
    }
}

// ---------------- launcher ----------------
extern "C" void kernel_launch(void* const* d_in, const int* in_sizes, int n_in,
                              void* d_out, int out_size, void* d_ws, size_t ws_size,
                              hipStream_t stream) {
    const float* query = (const float*)d_in[0];
    const float* skipq = (const float*)d_in[1];
    const float* Wqkv  = (const float*)d_in[2];
    const float* bqkv  = (const float*)d_in[3];
    const float* Wskip = (const float*)d_in[4];
    const float* bskip = (const float*)d_in[5];
    const float* rpb   = (const float*)d_in[6];
    const float* Wproj = (const float*)d_in[7];
    const float* bproj = (const float*)d_in[8];
    float* out = (float*)d_out;

    int M = in_sizes[0] / 384;   // total tokens = 147456 for B=16
    int nwin = M / 64;           // 2304

    char* ws = (char*)d_ws;
    size_t off = 0;
    auto alloc = [&](size_t bytes) -> void* {
        void* p = ws + off;
        off = (off + bytes + 255) & ~(size_t)255;
        return p;
    };
    short* Wt     = (short*)alloc((size_t)1152 * 384 * 2);
    short* WtP    = (short*)alloc((size_t)384 * 384 * 2);
    float* bias64 = (float*)alloc((size_t)12 * 64 * 64 * 4);
    short* kbuf   = (short*)alloc((size_t)M * 384 * 2);
    short* vtbuf  = (short*)alloc((size_t)M * 384 * 2);
    short* qbuf   = (short*)alloc((size_t)M * 384 * 2);
    short* aout   = (short*)alloc((size_t)M * 384 * 2);
    (void)ws_size;

    hipLaunchKernelGGL(prep_wt, dim3(216), dim3(256), 0, stream, Wqkv, Wskip, Wt);
    hipLaunchKernelGGL(prep_wtp, dim3(72), dim3(256), 0, stream, Wproj, WtP);
    hipLaunchKernelGGL(prep_bias, dim3(192), dim3(256), 0, stream, rpb, bias64);
    hipLaunchKernelGGL(gemm_qkv, dim3(nwin, 2), dim3(768), 0, stream,
                       query, skipq, Wt, bqkv, bskip, kbuf, vtbuf, qbuf);
    hipLaunchKernelGGL(attn_kernel, dim3(nwin * 12 / 4), dim3(256), 0, stream,
                       kbuf, vtbuf, qbuf, bias64, aout, nwin * 12);
    hipLaunchKernelGGL(gemm_proj, dim3(nwin), dim3(768), 0, stream,
                       aout, WtP, bproj, out);
}

// Round 12
// 505.105 us; speedup vs baseline: 1.2739x; 1.2739x over previous
//
#include <hip/hip_runtime.h>
#include <hip/hip_bf16.h>

// ShiftWindowMSA fused pipeline for MI355X (gfx950).
// R12: barrier-free K-loops (R10 machinery) with m97-geometry fat wave tiles.
// Block = 1 window, 256 thr (4 waves). A[64][384] bf16 resident in LDS; each
// wave owns 64 output cols end-to-end: per step 4 A-frags + 4 B-frags
// (ds_read_b128) + 16 MFMA. B staged wave-private via global_load_lds
// (4 KB dbuf/wave, counted vmcnt(4), lgkm-protected, no K-loop barriers).
// var0: 3 passes (k,k),(k,v),(v,v); var1: q in 1-2 passes. 80 KB -> 2 blk/CU.

typedef __attribute__((ext_vector_type(8))) short short8;
typedef __attribute__((ext_vector_type(4))) float floatx4;

#define MFMA16(a, b, c) __builtin_amdgcn_mfma_f32_16x16x32_bf16(a, b, c, 0, 0, 0)

__device__ __forceinline__ short f2bf(float f) {
    __hip_bfloat16 h = __float2bfloat16(f);
    return *reinterpret_cast<short*>(&h);
}

// packed fp32->bf16 RNE
__device__ __forceinline__ unsigned cvt2bf(float lo, float hi) {
    unsigned r;
    asm("v_cvt_pk_bf16_f32 %0, %1, %2" : "=v"(r) : "v"(lo), "v"(hi));
    return r;
}

__device__ __forceinline__ void glds16(const void* g, void* l) {
    __builtin_amdgcn_global_load_lds(
        (const __attribute__((address_space(1))) void*)g,
        (__attribute__((address_space(3))) void*)l, 16, 0, 0);
}

// ---------------- prep kernels ----------------

__global__ __launch_bounds__(256) void prep_wt(const float* __restrict__ Wqkv,
                                               const float* __restrict__ Wskip,
                                               short* __restrict__ Wt) {
    int tid = blockIdx.x * 256 + threadIdx.x;  // 384*144 = 55296
    if (tid >= 384 * 144) return;
    int k = tid / 144;
    int n8 = (tid % 144) * 8;
#pragma unroll
    for (int e = 0; e < 8; e++) {
        int n = n8 + e;
        float v = (n < 768) ? Wqkv[k * 768 + n]
                            : Wskip[k * 384 + (n - 768)] * 0.17677669529663687f;
        Wt[(size_t)n * 384 + k] = f2bf(v);
    }
}

__global__ __launch_bounds__(256) void prep_wtp(const float* __restrict__ Wproj,
                                                short* __restrict__ WtP) {
    int tid = blockIdx.x * 256 + threadIdx.x;  // 384*48 = 18432
    if (tid >= 384 * 48) return;
    int k = tid / 48;
    int n8 = (tid % 48) * 8;
#pragma unroll
    for (int e = 0; e < 8; e++) {
        int n = n8 + e;
        WtP[(size_t)n * 384 + k] = f2bf(Wproj[k * 384 + n]);
    }
}

__global__ __launch_bounds__(256) void prep_bias(const float* __restrict__ rpb,
                                                 float* __restrict__ bias64) {
    int tid = blockIdx.x * 256 + threadIdx.x;  // 12*64*64 = 49152
    if (tid >= 49152) return;
    int h = tid >> 12;
    int rem = tid & 4095;
    int i = rem >> 6, kk = rem & 63;
    int j = 63 - kk;
    int ridx = 15 * (i >> 3) + (i & 7) + 15 * (j >> 3) + (j & 7);
    bias64[tid] = rpb[ridx * 12 + h];
}

// ---------------- per-wave barrier-free 12-step K-loop (wave tile 64x64) ----
// A in smemA[0..24576) chunk-swizzled (c ^ (r&7)); wave B dbuf bwb (2x2048 sh).
// Step kt: vmcnt wait, read 4 A + 4 B frags from half kt&1, lgkmcnt(0),
// issue 4 glds (step kt+2, or next pass's 0/1) into half kt&1, 16 MFMA.
__device__ __forceinline__ void kloop12f(
    const short* __restrict__ smemA, short* __restrict__ bwb,
    const short* __restrict__ curSrc, const short* __restrict__ nxtSrc,
    const int (&bso)[4], int l15, int g4, int al7, int brd,
    bool swapped, floatx4 (&acc)[4][4]) {
#pragma unroll
    for (int a = 0; a < 4; a++)
#pragma unroll
        for (int b = 0; b < 4; b++)
#pragma unroll
            for (int r = 0; r < 4; r++) acc[a][b][r] = 0.f;
    const bool fin = (nxtSrc == nullptr);
#pragma unroll
    for (int kt = 0; kt < 12; ++kt) {
        if (fin && kt == 11) asm volatile("s_waitcnt vmcnt(0)" ::: "memory");
        else                 asm volatile("s_waitcnt vmcnt(4)" ::: "memory");
        const int choff = ((kt * 4 + g4) ^ al7) * 8;
        short8 af[4], bfr[4];
        short* hb = bwb + (kt & 1) * 2048;
#pragma unroll
        for (int b = 0; b < 4; b++)
            af[b] = *(const short8*)(smemA + (b * 16 + l15) * 384 + choff);
#pragma unroll
        for (int a = 0; a < 4; a++)
            bfr[a] = *(const short8*)(hb + (a * 16 + l15) * 32 + brd);
        __builtin_amdgcn_sched_barrier(0);
        asm volatile("s_waitcnt lgkmcnt(0)" ::: "memory");
        if (kt < 10) {
            int ko = (kt + 2) * 32;
#pragma unroll
            for (int j = 0; j < 4; j++) glds16(curSrc + bso[j] + ko, hb + j * 512);
        } else if (!fin) {
            int ko = (kt - 10) * 32;
#pragma unroll
            for (int j = 0; j < 4; j++) glds16(nxtSrc + bso[j] + ko, hb + j * 512);
        }
        __builtin_amdgcn_sched_barrier(0);
        if (swapped) {
#pragma unroll
            for (int a = 0; a < 4; a++)
#pragma unroll
                for (int b = 0; b < 4; b++)
                    acc[a][b] = MFMA16(bfr[a], af[b], acc[a][b]);
        } else {
#pragma unroll
            for (int a = 0; a < 4; a++)
#pragma unroll
                for (int b = 0; b < 4; b++)
                    acc[a][b] = MFMA16(af[b], bfr[a], acc[a][b]);
        }
    }
}

// ---------------- gemm_qkv ----------------
// LDS: A[64][384] 48 KB @0; 4 waves x dbuf(2x4KB) @24576. 80 KB -> 2 blk/CU.
__global__ __launch_bounds__(256, 2) void gemm_qkv(
    const float* __restrict__ xq, const float* __restrict__ xs,
    const short* __restrict__ Wt,
    const float* __restrict__ bqkv, const float* __restrict__ bskip,
    short* __restrict__ kbuf, short* __restrict__ vtbuf, short* __restrict__ qbuf) {
    __shared__ short smem[40960];

    const int win = blockIdx.x;
    const int var = blockIdx.y;          // 0: A=query -> k,v; 1: A=skip -> q
    const float* __restrict__ src = var ? xs : xq;

    const int tid = threadIdx.x, lane = tid & 63, wid = tid >> 6;
    const int l15 = lane & 15, g4 = lane >> 4;
    const int al7 = l15 & 7;
    const int brd = (g4 ^ ((l15 ^ (l15 >> 2)) & 3)) * 8;

    // ---- A gather: 64 rows x 384 fp32 (shift-window permuted) -> bf16 LDS ----
    {
        int r = tid >> 2, q4 = tid & 3;
        int b = win / 144, wr = win % 144;
        int wy = wr / 12, wx = wr % 12;
        int yy = wy * 8 + (r >> 3) + 4; if (yy >= 96) yy -= 96;
        int xx = wx * 8 + (r & 7) + 4;  if (xx >= 96) xx -= 96;
        const float* rbase = src + ((size_t)b * 9216 + yy * 96 + xx) * 384;
        short* lrow = smem + r * 384;
        int r7 = r & 7;
#pragma unroll
        for (int j = 0; j < 12; j++) {
            int c = q4 + j * 4;
            float4 f0 = *(const float4*)(rbase + c * 8);
            float4 f1 = *(const float4*)(rbase + c * 8 + 4);
            uint4 u;
            u.x = cvt2bf(f0.x, f0.y); u.y = cvt2bf(f0.z, f0.w);
            u.z = cvt2bf(f1.x, f1.y); u.w = cvt2bf(f1.z, f1.w);
            *(uint4*)(lrow + ((c ^ r7) * 8)) = u;
        }
    }

    // ---- wave-private B staging roles: 4 glds of 1 KB per step (64 rows) ----
    const int swst = ((lane >> 2) ^ (lane >> 4)) & 3;
    int bso[4];
#pragma unroll
    for (int j = 0; j < 4; j++)
        bso[j] = (j * 16 + (lane >> 2)) * 384 + (((lane & 3) ^ swst) * 8);
    short* bwb = smem + 24576 + wid * 4096;

    // per-wave column strips
    const int wpair = wid >> 1, wn = wid & 1;
    int pcol = var ? (768 + wid * 64) : (wpair * 128 + wn * 64);
    const short* cur = Wt + (size_t)pcol * 384;

    // prologue: stage steps 0,1 of first pass
#pragma unroll
    for (int j = 0; j < 4; j++) glds16(cur + bso[j], bwb + j * 512);
#pragma unroll
    for (int j = 0; j < 4; j++) glds16(cur + bso[j] + 32, bwb + 2048 + j * 512);
    __syncthreads();  // A ready; drains all counters

    floatx4 acc[4][4];
    const float scl = 0.17677669529663687f;

    auto epi_k = [&](int pc) {
#pragma unroll
        for (int a = 0; a < 4; a++) {
            int nm = pc + a * 16 + g4 * 4;
            int head = nm >> 5, d0 = nm & 31;
            float4 bv = *(const float4*)(bqkv + nm);
            short* dst = kbuf + (size_t)(win * 12 + head) * 2048 + d0;
#pragma unroll
            for (int b = 0; b < 4; b++) {
                int t = b * 16 + l15;
                uint2 pk;
                pk.x = cvt2bf(acc[a][b][0] + bv.x, acc[a][b][1] + bv.y);
                pk.y = cvt2bf(acc[a][b][2] + bv.z, acc[a][b][3] + bv.w);
                *(uint2*)(dst + (size_t)t * 32) = pk;
            }
        }
    };
    auto epi_v = [&](int pc) {
#pragma unroll
        for (int nj = 0; nj < 4; nj++) {
            int nm = pc + nj * 16 + l15 - 384;
            int head = nm >> 5, d = nm & 31;
            float bvs = bqkv[384 + nm];
            short* dst = vtbuf + ((size_t)(win * 12 + head) * 32 + d) * 64;
#pragma unroll
            for (int mi = 0; mi < 4; mi++) {
                int t0 = mi * 16 + g4 * 4;
                uint2 pk;
                pk.x = cvt2bf(acc[nj][mi][0] + bvs, acc[nj][mi][1] + bvs);
                pk.y = cvt2bf(acc[nj][mi][2] + bvs, acc[nj][mi][3] + bvs);
                *(uint2*)(dst + t0) = pk;
            }
        }
    };
    auto epi_q = [&](int pc) {
#pragma unroll
        for (int a = 0; a < 4; a++) {
            int nm = pc + a * 16 + g4 * 4 - 768;
            int head = nm >> 5, d0 = nm & 31;
            float4 bv = *(const float4*)(bskip + nm);
            short* dst = qbuf + (size_t)(win * 12 + head) * 2048 + d0;
#pragma unroll
            for (int b = 0; b < 4; b++) {
                int t = b * 16 + l15;
                uint2 pk;
                pk.x = cvt2bf(acc[a][b][0] + bv.x * scl, acc[a][b][1] + bv.y * scl);
                pk.y = cvt2bf(acc[a][b][2] + bv.z * scl, acc[a][b][3] + bv.w * scl);
                *(uint2*)(dst + (size_t)t * 32) = pk;
            }
        }
    };

    if (var == 0) {
        // pass0: panels {0,1} (k,k); pass1: {2,3} (k,v); pass2: {4,5} (v,v)
        const short* nxt = cur + (size_t)256 * 384;
        kloop12f(smem, bwb, cur, nxt, bso, l15, g4, al7, brd, true, acc);
        epi_k(pcol);
        pcol += 256; cur = nxt; nxt = cur + (size_t)256 * 384;
        bool swp1 = (wpair == 0);  // panel 2 = k, panel 3 = v
        kloop12f(smem, bwb, cur, nxt, bso, l15, g4, al7, brd, swp1, acc);
        if (swp1) epi_k(pcol); else epi_v(pcol);
        pcol += 256; cur = nxt;
        kloop12f(smem, bwb, cur, nullptr, bso, l15, g4, al7, brd, false, acc);
        epi_v(pcol);
    } else {
        // pass0: panels {6,7} (q); pass1: panel 8 (q), waves 0,1 only
        const short* nxt = (wid < 2) ? Wt + (size_t)(1024 + wid * 64) * 384 : nullptr;
        kloop12f(smem, bwb, cur, nxt, bso, l15, g4, al7, brd, true, acc);
        epi_q(pcol);
        if (wid < 2) {
            kloop12f(smem, bwb, nxt, nullptr, bso, l15, g4, al7, brd, true, acc);
            epi_q(1024 + wid * 64);
        }
    }
}

// ---------------- attention (R7-proven) ----------------
__global__ __launch_bounds__(256) void attn_kernel(
    const short* __restrict__ kbuf, const short* __restrict__ vtbuf,
    const short* __restrict__ qbuf, const float* __restrict__ bias64,
    short* __restrict__ aout, int ntask) {
    __shared__ short lps[18432];  // 4 waves x 64 x 72
    int lane = threadIdx.x & 63, wid = threadIdx.x >> 6;
    int task = blockIdx.x * 4 + wid;
    if (task >= ntask) return;
    int win = task / 12, head = task % 12;
    int l15 = lane & 15, g4 = lane >> 4;

    const short* kb = kbuf + (size_t)task * 2048;
    const short* qb = qbuf + (size_t)task * 2048;
    const short* vb = vtbuf + (size_t)task * 2048;

    short8 kf[4], qf[4], vf[2][2];
#pragma unroll
    for (int mi = 0; mi < 4; mi++)
        kf[mi] = *(const short8*)(kb + (mi * 16 + l15) * 32 + g4 * 8);
#pragma unroll
    for (int nj = 0; nj < 4; nj++)
        qf[nj] = *(const short8*)(qb + (nj * 16 + l15) * 32 + g4 * 8);
#pragma unroll
    for (int ma = 0; ma < 2; ma++)
#pragma unroll
        for (int ks = 0; ks < 2; ks++)
            vf[ma][ks] = *(const short8*)(vb + (ma * 16 + l15) * 64 + ks * 32 + g4 * 8);

    floatx4 st[4][4];
#pragma unroll
    for (int mi = 0; mi < 4; mi++)
#pragma unroll
        for (int nj = 0; nj < 4; nj++)
#pragma unroll
            for (int r = 0; r < 4; r++) st[mi][nj][r] = 0.f;

#pragma unroll
    for (int mi = 0; mi < 4; mi++)
#pragma unroll
        for (int nj = 0; nj < 4; nj++)
            st[mi][nj] = MFMA16(kf[mi], qf[nj], st[mi][nj]);  // S^T[kk][i]

    const float* bb = bias64 + head * 4096;
#pragma unroll
    for (int nj = 0; nj < 4; nj++) {
        int i = nj * 16 + l15;
#pragma unroll
        for (int mi = 0; mi < 4; mi++) {
            floatx4 b4 = *(const floatx4*)(bb + i * 64 + mi * 16 + g4 * 4);
            st[mi][nj] += b4;
        }
    }

    int wr = win % 144;
    int wy = wr / 12, wx = wr % 12;
    if (wy == 11 || wx == 11) {
        int wy11 = (wy == 11), wx11 = (wx == 11);
        int ri[4];
#pragma unroll
        for (int nj = 0; nj < 4; nj++) {
            int t = nj * 16 + l15;
            int hh = wy11 ? (((t >> 3) >= 4) ? 2 : 1) : 0;
            int ww = wx11 ? (((t & 7) >= 4) ? 2 : 1) : 0;
            ri[nj] = hh * 3 + ww;
        }
#pragma unroll
        for (int mi = 0; mi < 4; mi++)
#pragma unroll
            for (int r = 0; r < 4; r++) {
                int t = mi * 16 + g4 * 4 + r;
                int hh = wy11 ? (((t >> 3) >= 4) ? 2 : 1) : 0;
                int ww = wx11 ? (((t & 7) >= 4) ? 2 : 1) : 0;
                int rk = hh * 3 + ww;
#pragma unroll
                for (int nj = 0; nj < 4; nj++)
                    if (rk != ri[nj]) st[mi][nj][r] -= 100.0f;
            }
    }

    float rden[4];
#pragma unroll
    for (int nj = 0; nj < 4; nj++) {
        float m = -1e30f;
#pragma unroll
        for (int mi = 0; mi < 4; mi++)
#pragma unroll
            for (int r = 0; r < 4; r++) m = fmaxf(m, st[mi][nj][r]);
        m = fmaxf(m, __shfl_xor(m, 16));
        m = fmaxf(m, __shfl_xor(m, 32));
        float s = 0.f;
#pragma unroll
        for (int mi = 0; mi < 4; mi++)
#pragma unroll
            for (int r = 0; r < 4; r++) {
                float p = __expf(st[mi][nj][r] - m);
                st[mi][nj][r] = p;
                s += p;
            }
        s += __shfl_xor(s, 16);
        s += __shfl_xor(s, 32);
        rden[nj] = 1.0f / s;
    }

    short* Lp = lps + wid * 4608;  // [64][72]
#pragma unroll
    for (int mi = 0; mi < 4; mi++)
#pragma unroll
        for (int nj = 0; nj < 4; nj++) {
            uint2 pk;
            pk.x = cvt2bf(st[mi][nj][0], st[mi][nj][1]);
            pk.y = cvt2bf(st[mi][nj][2], st[mi][nj][3]);
            *(uint2*)(Lp + (nj * 16 + l15) * 72 + mi * 16 + g4 * 4) = pk;
        }

    floatx4 o[2][4];
#pragma unroll
    for (int ma = 0; ma < 2; ma++)
#pragma unroll
        for (int nj = 0; nj < 4; nj++)
#pragma unroll
            for (int r = 0; r < 4; r++) o[ma][nj][r] = 0.f;
#pragma unroll
    for (int ks = 0; ks < 2; ks++) {
        short8 pb[4];
#pragma unroll
        for (int nj = 0; nj < 4; nj++)
            pb[nj] = *(const short8*)(Lp + (nj * 16 + l15) * 72 + ks * 32 + g4 * 8);
#pragma unroll
        for (int ma = 0; ma < 2; ma++)
#pragma unroll
            for (int nj = 0; nj < 4; nj++)
                o[ma][nj] = MFMA16(vf[ma][ks], pb[nj], o[ma][nj]);
    }

    short* ob = aout + (size_t)win * 64 * 384 + head * 32;
#pragma unroll
    for (int ma = 0; ma < 2; ma++)
#pragma unroll
        for (int nj = 0; nj < 4; nj++) {
            int i = nj * 16 + l15;
            uint2 pk;
            pk.x = cvt2bf(o[ma][nj][0] * rden[nj], o[ma][nj][1] * rden[nj]);
            pk.y = cvt2bf(o[ma][nj][2] * rden[nj], o[ma][nj][3] * rden[nj]);
            *(uint2*)(ob + (size_t)i * 384 + ma * 16 + g4 * 4) = pk;
        }
}

// ---------------- gemm_proj ----------------
__global__ __launch_bounds__(256, 2) void gemm_proj(
    const short* __restrict__ aout, const short* __restrict__ WtP,
    const float* __restrict__ bproj, float* __restrict__ out) {
    __shared__ short smem[40960];

    const int win = blockIdx.x;
    const int m0 = win * 64;
    const int tid = threadIdx.x, lane = tid & 63, wid = tid >> 6;
    const int l15 = lane & 15, g4 = lane >> 4;
    const int al7 = l15 & 7;
    const int brd = (g4 ^ ((l15 ^ (l15 >> 2)) & 3)) * 8;

    // ---- A via glds: 48 issues of 1 KB (12 per wave), pre-swizzled source ----
#pragma unroll
    for (int j = 0; j < 12; j++) {
        int i = wid * 12 + j;
        int c = i * 64 + lane;
        int row = c / 48, ch = c - row * 48;
        const short* s = aout + (size_t)(m0 + row) * 384 + ((ch ^ (row & 7)) * 8);
        glds16(s, smem + i * 512);
    }

    const int swst = ((lane >> 2) ^ (lane >> 4)) & 3;
    int bso[4];
#pragma unroll
    for (int j = 0; j < 4; j++)
        bso[j] = (j * 16 + (lane >> 2)) * 384 + (((lane & 3) ^ swst) * 8);
    short* bwb = smem + 24576 + wid * 4096;

    int pcol = wid * 64;  // pass0 covers panels 0,1 (cols 0..255)
    const short* cur = WtP + (size_t)pcol * 384;
#pragma unroll
    for (int j = 0; j < 4; j++) glds16(cur + bso[j], bwb + j * 512);
#pragma unroll
    for (int j = 0; j < 4; j++) glds16(cur + bso[j] + 32, bwb + 2048 + j * 512);
    __syncthreads();

    const int b_img = win / 144, wrw = win % 144;
    const int wy = wrw / 12, wx = wrw % 12;

    floatx4 acc[4][4];
    auto epi = [&](int pc) {
#pragma unroll
        for (int a = 0; a < 4; a++) {
            int n = pc + a * 16 + g4 * 4;
            float4 bv = *(const float4*)(bproj + n);
#pragma unroll
            for (int b = 0; b < 4; b++) {
                int t = b * 16 + l15;
                int yy = wy * 8 + (t >> 3) + 4; if (yy >= 96) yy -= 96;
                int xx = wx * 8 + (t & 7) + 4;  if (xx >= 96) xx -= 96;
                floatx4 o = acc[a][b];
                o[0] += bv.x; o[1] += bv.y; o[2] += bv.z; o[3] += bv.w;
                *(floatx4*)(&out[((size_t)b_img * 9216 + yy * 96 + xx) * 384 + n]) = o;
            }
        }
    };

    const short* nxt = (wid < 2) ? WtP + (size_t)(256 + wid * 64) * 384 : nullptr;
    kloop12f(smem, bwb, cur, nxt, bso, l15, g4, al7, brd, true, acc);
    epi(pcol);
    if (wid < 2) {
        kloop12f(smem, bwb, nxt, nullptr, bso, l15, g4, al7, brd, true, acc);
        epi(256 + wid * 64);
    }
}

// ---------------- launcher ----------------
extern "C" void kernel_launch(void* const* d_in, const int* in_sizes, int n_in,
                              void* d_out, int out_size, void* d_ws, size_t ws_size,
                              hipStream_t stream) {
    const float* query = (const float*)d_in[0];
    const float* skipq = (const float*)d_in[1];
    const float* Wqkv  = (const float*)d_in[2];
    const float* bqkv  = (const float*)d_in[3];
    const float* Wskip = (const float*)d_in[4];
    const float* bskip = (const float*)d_in[5];
    const float* rpb   = (const float*)d_in[6];
    const float* Wproj = (const float*)d_in[7];
    const float* bproj = (const float*)d_in[8];
    float* out = (float*)d_out;

    int M = in_sizes[0] / 384;   // total tokens = 147456 for B=16
    int nwin = M / 64;           // 2304

    char* ws = (char*)d_ws;
    size_t off = 0;
    auto alloc = [&](size_t bytes) -> void* {
        void* p = ws + off;
        off = (off + bytes + 255) & ~(size_t)255;
        return p;
    };
    short* Wt     = (short*)alloc((size_t)1152 * 384 * 2);
    short* WtP    = (short*)alloc((size_t)384 * 384 * 2);
    float* bias64 = (float*)alloc((size_t)12 * 64 * 64 * 4);
    short* kbuf   = (short*)alloc((size_t)M * 384 * 2);
    short* vtbuf  = (short*)alloc((size_t)M * 384 * 2);
    short* qbuf   = (short*)alloc((size_t)M * 384 * 2);
    short* aout   = (short*)alloc((size_t)M * 384 * 2);
    (void)ws_size;

    hipLaunchKernelGGL(prep_wt, dim3(216), dim3(256), 0, stream, Wqkv, Wskip, Wt);
    hipLaunchKernelGGL(prep_wtp, dim3(72), dim3(256), 0, stream, Wproj, WtP);
    hipLaunchKernelGGL(prep_bias, dim3(192), dim3(256), 0, stream, rpb, bias64);
    hipLaunchKernelGGL(gemm_qkv, dim3(nwin, 2), dim3(256), 0, stream,
                       query, skipq, Wt, bqkv, bskip, kbuf, vtbuf, qbuf);
    hipLaunchKernelGGL(attn_kernel, dim3(nwin * 12 / 4), dim3(256), 0, stream,
                       kbuf, vtbuf, qbuf, bias64, aout, nwin * 12);
    hipLaunchKernelGGL(gemm_proj, dim3(nwin), dim3(256), 0, stream,
                       aout, WtP, bproj, out);
}